// Round 1
// baseline (537.502 us; speedup 1.0000x reference)
//
#include <hip/hip_runtime.h>
#include <stdint.h>

// mGRU fused: B=8, S=2048, IN=1024, HID=1024
//   M = 16384 rows, K = 2048, N = 1024
// Strategy: bf16 MFMA (16x16x32), m97-style 128x128 tile, global_load_lds staging.

#define M_ROWS 16384
#define K_DIM  2048
#define N_DIM  1024

typedef float  f32x4  __attribute__((ext_vector_type(4)));
typedef __bf16 bf16x8 __attribute__((ext_vector_type(8)));
typedef unsigned short u16x8 __attribute__((ext_vector_type(8)));

typedef __attribute__((address_space(3))) void as3_void;
typedef __attribute__((address_space(1))) void as1_void;

__device__ __forceinline__ void gload_lds16(const unsigned short* g, void* lds) {
    // 16B per lane; LDS dest = wave-uniform base + lane*16 (linear), global src per-lane.
    __builtin_amdgcn_global_load_lds((const as1_void*)g, (as3_void*)lds, 16, 0, 0);
}

__device__ __forceinline__ unsigned short f2bf(float f) {
    union { float f; unsigned u; } v; v.f = f;
    unsigned r = 0x7FFFu + ((v.u >> 16) & 1u);
    return (unsigned short)((v.u + r) >> 16);
}

// ---------------- pack kernels ----------------

// A_bf[row][c] = c<1024 ? x[row][c] : h[row][c-1024]   (bf16)
__global__ void pack_A(const float* __restrict__ x, const float* __restrict__ h,
                       unsigned short* __restrict__ Abf) {
    size_t t = (size_t)blockIdx.x * blockDim.x + threadIdx.x;   // 4,194,304 threads
    size_t e = t * 8;                                           // 8 elems/thread
    int row = (int)(e >> 11);
    int col = (int)(e & 2047);
    const float* src = (col < 1024) ? (x + (size_t)row * 1024 + col)
                                    : (h + (size_t)row * 1024 + (col - 1024));
    f32x4 v0 = ((const f32x4*)src)[0];
    f32x4 v1 = ((const f32x4*)src)[1];
    u16x8 o;
    o[0] = f2bf(v0[0]); o[1] = f2bf(v0[1]); o[2] = f2bf(v0[2]); o[3] = f2bf(v0[3]);
    o[4] = f2bf(v1[0]); o[5] = f2bf(v1[1]); o[6] = f2bf(v1[2]); o[7] = f2bf(v1[3]);
    *(u16x8*)(Abf + e) = o;
}

__global__ void pack_W(const float* __restrict__ W1, const float* __restrict__ W2,
                       unsigned short* __restrict__ W1b, unsigned short* __restrict__ W2b) {
    size_t t = (size_t)blockIdx.x * blockDim.x + threadIdx.x;   // 524,288 threads
    size_t e = t * 8;                                           // 4,194,304 elems total
    int which = (int)(e >> 21);                                 // 2,097,152 per weight
    size_t e2 = e & ((1u << 21) - 1);
    const float* src = (which ? W2 : W1) + e2;
    unsigned short* dst = (which ? W2b : W1b) + e2;
    f32x4 v0 = ((const f32x4*)src)[0];
    f32x4 v1 = ((const f32x4*)src)[1];
    u16x8 o;
    o[0] = f2bf(v0[0]); o[1] = f2bf(v0[1]); o[2] = f2bf(v0[2]); o[3] = f2bf(v0[3]);
    o[4] = f2bf(v1[0]); o[5] = f2bf(v1[1]); o[6] = f2bf(v1[2]); o[7] = f2bf(v1[3]);
    *(u16x8*)dst = o;
}

// ---------------- GEMM kernels (m97 structure: 128x128 tile, BK=32, 4 waves) ----------------
// C[m][n] = sum_k A[m][k] * W[n][k]  (both K-contiguous row-major)

__global__ __launch_bounds__(256) void gemm1(
        const unsigned short* __restrict__ Abf,  // [M][2048] bf16
        const unsigned short* __restrict__ Wb,   // [1024][2048] bf16
        const float* __restrict__ bias,          // [1024]
        const float* __restrict__ h,             // [M][1024] fp32
        float* Fout,                             // [M][1024] fp32 (d_out scratch)
        unsigned short* __restrict__ H2)         // [M][1024] bf16 (interim_h)
{
    __shared__ unsigned short As[128 * 32];
    __shared__ unsigned short Bs[128 * 32];

    int bid = blockIdx.x;
    int wg  = (bid & 7) * 128 + (bid >> 3);      // XCD-bijective swizzle (1024 % 8 == 0)
    int tn = wg & 7, tm = wg >> 3;
    int m0 = tm * 128, n0 = tn * 128;

    int t = threadIdx.x, wave = t >> 6, lane = t & 63;
    int wr = wave >> 1, wc = wave & 1;           // wave -> 64x64 quadrant
    int fr = lane & 15, fq = lane >> 4;
    int sRow = t >> 2, sCol = (t & 3) * 8;       // staging: 4 lanes/row, 8 bf16 each

    const unsigned short* aBase = Abf + (size_t)(m0 + sRow) * K_DIM + sCol;
    const unsigned short* bBase = Wb  + (size_t)(n0 + sRow) * K_DIM + sCol;
    char* AsB = (char*)As;  char* BsB = (char*)Bs;
    int ldsW = wave * 1024;                      // wave-uniform chunk base (bytes)

    f32x4 acc[4][4] = {};

    for (int k0 = 0; k0 < K_DIM; k0 += 32) {
        gload_lds16(aBase + k0,                AsB + ldsW);
        gload_lds16(aBase + 64 * K_DIM + k0,   AsB + 4096 + ldsW);
        gload_lds16(bBase + k0,                BsB + ldsW);
        gload_lds16(bBase + 64 * K_DIM + k0,   BsB + 4096 + ldsW);
        __syncthreads();                          // drains vmcnt -> LDS ready
        bf16x8 af[4], bfr[4];
#pragma unroll
        for (int i = 0; i < 4; i++) {
            af[i]  = *(const bf16x8*)&As[(wr * 64 + i * 16 + fr) * 32 + fq * 8];
            bfr[i] = *(const bf16x8*)&Bs[(wc * 64 + i * 16 + fr) * 32 + fq * 8];
        }
#pragma unroll
        for (int mi = 0; mi < 4; mi++)
#pragma unroll
            for (int ni = 0; ni < 4; ni++)
                acc[mi][ni] = __builtin_amdgcn_mfma_f32_16x16x32_bf16(
                                  af[mi], bfr[ni], acc[mi][ni], 0, 0, 0);
        __syncthreads();                          // protect LDS before next overwrite
    }

    // epilogue: f = sigmoid(c + b1); Fout = f; H2 = bf16(f*h)
    int rowBase = m0 + wr * 64 + fq * 4;
    int colBase = n0 + wc * 64 + fr;
#pragma unroll
    for (int mi = 0; mi < 4; mi++) {
#pragma unroll
        for (int ni = 0; ni < 4; ni++) {
            int col = colBase + ni * 16;
            float b = bias[col];
#pragma unroll
            for (int j = 0; j < 4; j++) {
                int row = rowBase + mi * 16 + j;
                size_t idx = (size_t)row * N_DIM + col;
                float c = acc[mi][ni][j] + b;
                float f = 1.0f / (1.0f + expf(-c));
                Fout[idx] = f;
                float hv = h[idx];
                H2[idx] = f2bf(f * hv);
            }
        }
    }
}

__global__ __launch_bounds__(256) void gemm2(
        const unsigned short* __restrict__ Abf,  // [M][2048] bf16 (x in cols 0..1023)
        const unsigned short* __restrict__ H2,   // [M][1024] bf16 (interim_h)
        const unsigned short* __restrict__ Wb,   // [1024][2048] bf16
        const float* __restrict__ bias,          // [1024]
        const float* __restrict__ h,             // [M][1024] fp32
        float* Fout,                             // [M][1024] fp32 (reads f, then overwritten)
        float* Out2)                             // second tuple copy
{
    __shared__ unsigned short As[128 * 32];
    __shared__ unsigned short Bs[128 * 32];

    int bid = blockIdx.x;
    int wg  = (bid & 7) * 128 + (bid >> 3);
    int tn = wg & 7, tm = wg >> 3;
    int m0 = tm * 128, n0 = tn * 128;

    int t = threadIdx.x, wave = t >> 6, lane = t & 63;
    int wr = wave >> 1, wc = wave & 1;
    int fr = lane & 15, fq = lane >> 4;
    int sRow = t >> 2, sCol = (t & 3) * 8;

    const unsigned short* aBase1 = Abf + (size_t)(m0 + sRow) * K_DIM + sCol;   // x half, lda 2048
    const unsigned short* aBase2 = H2  + (size_t)(m0 + sRow) * N_DIM + sCol;   // ih half, lda 1024
    const unsigned short* bBase  = Wb  + (size_t)(n0 + sRow) * K_DIM + sCol;
    char* AsB = (char*)As;  char* BsB = (char*)Bs;
    int ldsW = wave * 1024;

    f32x4 acc[4][4] = {};

    for (int k0 = 0; k0 < K_DIM; k0 += 32) {
        if (k0 < 1024) {
            gload_lds16(aBase1 + k0,               AsB + ldsW);
            gload_lds16(aBase1 + 64 * K_DIM + k0,  AsB + 4096 + ldsW);
        } else {
            int kk = k0 - 1024;
            gload_lds16(aBase2 + kk,               AsB + ldsW);
            gload_lds16(aBase2 + 64 * N_DIM + kk,  AsB + 4096 + ldsW);
        }
        gload_lds16(bBase + k0,                BsB + ldsW);
        gload_lds16(bBase + 64 * K_DIM + k0,   BsB + 4096 + ldsW);
        __syncthreads();
        bf16x8 af[4], bfr[4];
#pragma unroll
        for (int i = 0; i < 4; i++) {
            af[i]  = *(const bf16x8*)&As[(wr * 64 + i * 16 + fr) * 32 + fq * 8];
            bfr[i] = *(const bf16x8*)&Bs[(wc * 64 + i * 16 + fr) * 32 + fq * 8];
        }
#pragma unroll
        for (int mi = 0; mi < 4; mi++)
#pragma unroll
            for (int ni = 0; ni < 4; ni++)
                acc[mi][ni] = __builtin_amdgcn_mfma_f32_16x16x32_bf16(
                                  af[mi], bfr[ni], acc[mi][ni], 0, 0, 0);
        __syncthreads();
    }

    // epilogue: o = tanh(c + b2); out = h + f*(o - h); write both tuple copies
    int rowBase = m0 + wr * 64 + fq * 4;
    int colBase = n0 + wc * 64 + fr;
#pragma unroll
    for (int mi = 0; mi < 4; mi++) {
#pragma unroll
        for (int ni = 0; ni < 4; ni++) {
            int col = colBase + ni * 16;
            float b = bias[col];
#pragma unroll
            for (int j = 0; j < 4; j++) {
                int row = rowBase + mi * 16 + j;
                size_t idx = (size_t)row * N_DIM + col;
                float c = acc[mi][ni][j] + b;
                float o = tanhf(c);
                float f = Fout[idx];              // read BEFORE overwrite (same thread)
                float hv = h[idx];
                float out = fmaf(f, o - hv, hv);
                Fout[idx] = out;
                Out2[idx] = out;
            }
        }
    }
}

// ---------------- launch ----------------

extern "C" void kernel_launch(void* const* d_in, const int* in_sizes, int n_in,
                              void* d_out, int out_size, void* d_ws, size_t ws_size,
                              hipStream_t stream) {
    const float* x  = (const float*)d_in[0];
    const float* h  = (const float*)d_in[1];
    const float* W1 = (const float*)d_in[2];
    const float* b1 = (const float*)d_in[3];
    const float* W2 = (const float*)d_in[4];
    const float* b2 = (const float*)d_in[5];
    float* out = (float*)d_out;
    float* out2 = out + (size_t)M_ROWS * N_DIM;

    // workspace layout (109,051,904 bytes total)
    unsigned short* Abf = (unsigned short*)d_ws;                            // 67,108,864 B
    unsigned short* H2  = (unsigned short*)((char*)d_ws + 67108864);        // 33,554,432 B
    unsigned short* W1b = (unsigned short*)((char*)d_ws + 100663296);       //  4,194,304 B
    unsigned short* W2b = (unsigned short*)((char*)d_ws + 104857600);       //  4,194,304 B

    pack_A<<<16384, 256, 0, stream>>>(x, h, Abf);
    pack_W<<<2048, 256, 0, stream>>>(W1, W2, W1b, W2b);
    // gemm1: f = sigmoid(cat(x,h) @ W1^T + b1) -> Fout(=d_out half 1), H2 = bf16(f*h)
    gemm1<<<1024, 256, 0, stream>>>(Abf, W1b, b1, h, out, H2);
    // gemm2: o = tanh(cat(x,ih) @ W2^T + b2); out = h + f*(o-h) -> both halves
    gemm2<<<1024, 256, 0, stream>>>(Abf, H2, W2b, b2, h, out, out2);
}